// Round 6
// baseline (1033.361 us; speedup 1.0000x reference)
//
#include <hip/hip_runtime.h>
#include <hip/hip_bf16.h>
#include <hip/hip_cooperative_groups.h>

namespace cg = cooperative_groups;

typedef __bf16 bf16;
typedef __bf16 bf16x8 __attribute__((ext_vector_type(8)));
typedef float  f32x4  __attribute__((ext_vector_type(4)));

// ---------------------------------------------------------------------------
// NNConv, single cooperative mega-kernel (round 6):
//   Evidence r0-r5: (a) inter-dispatch gap ~12-15us x dispatch count is the
//   largest single cost (r0: 195us kernels vs 282 total; r4: 200 vs 394);
//   (b) accum phases are pure serial-latency (r4: 77us == waves x chain
//   latency, zero TLP overlap); (c) r5's 4-slot fix died to LDS promotion
//   (no launch_bounds -> VGPR=36 -> private arrays in LDS, occ 17%).
//   Fix: ONE hipLaunchCooperativeKernel with grid.sync() phases; accum uses
//   r4's verified lane mapping + 4 independent node chains per wave;
//   __launch_bounds__(256,4) keeps arrays in VGPRs. GEMM/bias-slice/pool
//   code byte-identical to r4 (verified).
// ---------------------------------------------------------------------------

struct MegaParams {
    const float *x, *ea;
    const float *W_e1a, *b_e1a, *W_e1b, *b_e1b, *root1, *bias1;
    const float *W_e2a, *b_e2a, *W_e2b, *b_e2b, *root2, *bias2;
    const int *eidx, *batch;
    int *deg, *rowptr, *cursor, *bsum, *boff;
    long long *edat;
    char *U1, *S1, *U2, *S2;
    float *r1, *h1, *r2;
    float *out_h, *out_g, *out_b;
    int N, E, Bg, ntiles, scanBlocks;
};

static __device__ inline unsigned short bfb(float f)
{
    __bf16 h = (__bf16)f;
    unsigned short u;
    __builtin_memcpy(&u, &h, 2);
    return u;
}

__global__ __launch_bounds__(256, 4) void mega(MegaParams p)
{
    cg::grid_group grid = cg::this_grid();
    const int tid      = blockIdx.x * blockDim.x + threadIdx.x;
    const int nthreads = gridDim.x * blockDim.x;
    const int lane     = threadIdx.x & 63;
    const int wave     = tid >> 6;
    const int nwaves   = nthreads >> 6;
    __shared__ int smem[256];

    // ---- P0: zero deg + node_pre1 (r1) + out_b passthrough ----
    for (int i = tid; i < p.N; i += nthreads) p.deg[i] = 0;
    for (int t = tid; t < p.N * 16; t += nthreads) {
        int v = t >> 4, o = t & 15;
        float racc = 0.f;
#pragma unroll
        for (int i = 0; i < 8; ++i)
            racc += p.x[v * 8 + i] * p.root1[i * 16 + o];
        p.r1[t] = racc + p.bias1[o];
    }
    for (int v = tid; v < p.N; v += nthreads) p.out_b[v] = (float)p.batch[v];
    grid.sync();

    // ---- P1: degree histogram ----
    for (int e = tid; e < p.E; e += nthreads)
        atomicAdd(&p.deg[p.eidx[p.E + e]], 1);
    grid.sync();

    // ---- P2a: per-256-chunk exclusive scan ----
    if ((int)blockIdx.x < p.scanBlocks) {
        const int t = threadIdx.x;
        const int i = blockIdx.x * 256 + t;
        int v = (i < p.N) ? p.deg[i] : 0;
        smem[t] = v;
        __syncthreads();
        for (int ofs = 1; ofs < 256; ofs <<= 1) {
            int add = (t >= ofs) ? smem[t - ofs] : 0;
            __syncthreads();
            smem[t] += add;
            __syncthreads();
        }
        if (i < p.N) p.rowptr[i] = smem[t] - v;
        if (t == 255) p.bsum[blockIdx.x] = smem[255];
    }
    grid.sync();

    // ---- P2b: top scan of chunk totals (block 0) ----
    if (blockIdx.x == 0) {
        const int t = threadIdx.x;
        int v = (t < p.scanBlocks) ? p.bsum[t] : 0;
        smem[t] = v;
        __syncthreads();
        for (int ofs = 1; ofs < 256; ofs <<= 1) {
            int add = (t >= ofs) ? smem[t - ofs] : 0;
            __syncthreads();
            smem[t] += add;
            __syncthreads();
        }
        if (t < p.scanBlocks) p.boff[t] = smem[t] - v;
    }
    grid.sync();

    // ---- P2c: add chunk offsets, init cursor ----
    for (int i = tid; i < p.N; i += nthreads) {
        int r = p.rowptr[i] + p.boff[i >> 8];
        p.rowptr[i] = r;
        p.cursor[i] = r;
    }
    if (tid == 0) p.rowptr[p.N] = p.E;
    grid.sync();

    // ---- P3: scatter edges into dst-sorted slots ----
    for (int e = tid; e < p.E; e += nthreads) {
        int d = p.eidx[p.E + e];
        int j = atomicAdd(&p.cursor[d], 1);
        long long pk = (long long)(unsigned)p.eidx[e]
                     | ((long long)__float_as_int(p.ea[e]) << 32);
        p.edat[j] = pk;
    }
    grid.sync();

    // ---- P4: edge accum layer 1 (r4 mapping, 4-node ILP) ----
    {
        const int j  = lane >> 2;
        const int il = lane & 3;
        const float wa = p.W_e1a[j], bb = p.b_e1a[j];
        for (int v0 = wave; v0 < p.N; v0 += 4 * nwaves) {
            int t[4], te[4];
            float u0[4], u1[4], s0[4], s1[4];
#pragma unroll
            for (int c = 0; c < 4; ++c) {
                int vc = v0 + c * nwaves;
                bool val = vc < p.N;
                t[c]  = val ? p.rowptr[vc] : 0;
                te[c] = val ? p.rowptr[vc + 1] : 0;
                u0[c] = u1[c] = s0[c] = s1[c] = 0.f;
            }
            while (true) {
                bool a[4]; bool any = false;
#pragma unroll
                for (int c = 0; c < 4; ++c) { a[c] = t[c] < te[c]; any |= a[c]; }
                if (!any) break;
#pragma unroll
                for (int c = 0; c < 4; ++c) {
                    long long ed = p.edat[a[c] ? t[c] : 0];
                    int   sv  = (int)(ed & 0xffffffffLL);
                    float eav = __int_as_float((int)(ed >> 32));
                    float m  = a[c] ? 1.f : 0.f;
                    float he = wa * eav + bb;
                    he = (he > 0.f ? he : 0.f) * m;
                    float2 xv = *(const float2*)(p.x + (size_t)sv * 8 + il * 2);
                    u0[c] += he * xv.x;  u1[c] += he * xv.y;
                    s0[c] += m  * xv.x;  s1[c] += m  * xv.y;
                    t[c] += a[c] ? 1 : 0;
                }
            }
#pragma unroll
            for (int c = 0; c < 4; ++c) {
                int vc = v0 + c * nwaves;
                if (vc < p.N) {
                    unsigned pk = (unsigned)bfb(u0[c]) | ((unsigned)bfb(u1[c]) << 16);
                    *(unsigned*)(p.U1 + (size_t)vc * 256 + lane * 4) = pk;
                    if (j == 0) {
                        unsigned ps = (unsigned)bfb(s0[c]) | ((unsigned)bfb(s1[c]) << 16);
                        *(unsigned*)(p.S1 + (size_t)vc * 16 + il * 4) = ps;
                    }
                }
            }
        }
    }
    grid.sync();

    // ---- P5: node GEMM layer 1 (r4-verified) + r2 precompute ----
    {
        const int m = lane & 15;
        const int q = lane >> 4;
        bf16x8 bfrag[4];
#pragma unroll
        for (int c = 0; c < 4; ++c)
#pragma unroll
            for (int t = 0; t < 8; ++t)
                bfrag[c][t] = (bf16)p.W_e1b[(t * 16 + m) * 16 + (c * 4 + q)];
        bf16x8 bfragb;
#pragma unroll
        for (int t = 0; t < 8; ++t)
            bfragb[t] = (q == 0) ? (bf16)p.b_e1b[t * 16 + m] : (bf16)0.f;
        float rt[16];
#pragma unroll
        for (int i = 0; i < 16; ++i) rt[i] = p.root2[i * 16 + m];
        const float b2 = p.bias2[m];

        for (int tile = wave; tile < p.ntiles; tile += nwaves) {
            const int v = tile * 16 + m;
            const char* arow = p.U1 + (size_t)v * 256;
            f32x4 acc = {0.f, 0.f, 0.f, 0.f};
            bf16x8 afs = *(const bf16x8*)(p.S1 + (size_t)v * 16);
            acc = __builtin_amdgcn_mfma_f32_16x16x32_bf16(afs, bfragb, acc, 0, 0, 0);
#pragma unroll
            for (int c = 0; c < 4; ++c) {
                bf16x8 af = *(const bf16x8*)(arow + c * 64 + q * 16);
                acc = __builtin_amdgcn_mfma_f32_16x16x32_bf16(af, bfrag[c], acc, 0, 0, 0);
            }
#pragma unroll
            for (int reg = 0; reg < 4; ++reg) {
                int vr = tile * 16 + q * 4 + reg;
                int vc = vr < p.N ? vr : p.N - 1;
                float cdeg = (float)p.deg[vc]; cdeg = cdeg > 1.f ? cdeg : 1.f;
                float h = acc[reg] / cdeg + p.r1[(size_t)vc * 16 + m];
                h = h > 0.f ? h : 0.f;
                float racc = b2;
#pragma unroll
                for (int i = 0; i < 16; ++i)
                    racc += __shfl(h, i, 16) * rt[i];
                if (vr < p.N) {
                    p.h1[(size_t)vr * 16 + m] = h;
                    p.r2[(size_t)vr * 16 + m] = racc;
                }
            }
        }
    }
    grid.sync();

    // ---- P6: edge accum layer 2 (4-node ILP) ----
    {
        const int j  = lane >> 2;
        const int il = lane & 3;
        const float wa = p.W_e2a[j], bb = p.b_e2a[j];
        for (int v0 = wave; v0 < p.N; v0 += 4 * nwaves) {
            int t[4], te[4];
            float u[4][4], s[4][4];
#pragma unroll
            for (int c = 0; c < 4; ++c) {
                int vc = v0 + c * nwaves;
                bool val = vc < p.N;
                t[c]  = val ? p.rowptr[vc] : 0;
                te[c] = val ? p.rowptr[vc + 1] : 0;
#pragma unroll
                for (int i = 0; i < 4; ++i) { u[c][i] = 0.f; s[c][i] = 0.f; }
            }
            while (true) {
                bool a[4]; bool any = false;
#pragma unroll
                for (int c = 0; c < 4; ++c) { a[c] = t[c] < te[c]; any |= a[c]; }
                if (!any) break;
#pragma unroll
                for (int c = 0; c < 4; ++c) {
                    long long ed = p.edat[a[c] ? t[c] : 0];
                    int   sv  = (int)(ed & 0xffffffffLL);
                    float eav = __int_as_float((int)(ed >> 32));
                    float m  = a[c] ? 1.f : 0.f;
                    float he = wa * eav + bb;
                    he = (he > 0.f ? he : 0.f) * m;
                    float4 hv = *(const float4*)(p.h1 + (size_t)sv * 16 + il * 4);
                    u[c][0] += he * hv.x;  u[c][1] += he * hv.y;
                    u[c][2] += he * hv.z;  u[c][3] += he * hv.w;
                    s[c][0] += m * hv.x;   s[c][1] += m * hv.y;
                    s[c][2] += m * hv.z;   s[c][3] += m * hv.w;
                    t[c] += a[c] ? 1 : 0;
                }
            }
#pragma unroll
            for (int c = 0; c < 4; ++c) {
                int vc = v0 + c * nwaves;
                if (vc < p.N) {
                    uint2 pk;
                    pk.x = (unsigned)bfb(u[c][0]) | ((unsigned)bfb(u[c][1]) << 16);
                    pk.y = (unsigned)bfb(u[c][2]) | ((unsigned)bfb(u[c][3]) << 16);
                    *(uint2*)(p.U2 + (size_t)vc * 512 + lane * 8) = pk;
                    if (j == 0) {
                        uint2 ps;
                        ps.x = (unsigned)bfb(s[c][0]) | ((unsigned)bfb(s[c][1]) << 16);
                        ps.y = (unsigned)bfb(s[c][2]) | ((unsigned)bfb(s[c][3]) << 16);
                        *(uint2*)(p.S2 + (size_t)vc * 32 + il * 8) = ps;
                    }
                }
            }
        }
    }
    grid.sync();

    // ---- P7: node GEMM layer 2 (r4-verified) -> out_h ----
    {
        const int m  = lane & 15;
        const int q  = lane >> 4;
        const int qh = q >> 1;
        const int ql = q & 1;
        bf16x8 bfrag[8];
#pragma unroll
        for (int c = 0; c < 8; ++c) {
            int j = c * 2 + qh;
#pragma unroll
            for (int t = 0; t < 8; ++t) {
                int i = ql * 8 + t;
                bfrag[c][t] = (bf16)p.W_e2b[(i * 16 + m) * 16 + j];
            }
        }
        bf16x8 bfragb;
#pragma unroll
        for (int t = 0; t < 8; ++t)
            bfragb[t] = (qh == 0) ? (bf16)p.b_e2b[(ql * 8 + t) * 16 + m] : (bf16)0.f;

        for (int tile = wave; tile < p.ntiles; tile += nwaves) {
            const int v = tile * 16 + m;
            const char* arow = p.U2 + (size_t)v * 512;
            f32x4 acc = {0.f, 0.f, 0.f, 0.f};
            bf16x8 afs = *(const bf16x8*)(p.S2 + (size_t)v * 32 + ql * 16);
            acc = __builtin_amdgcn_mfma_f32_16x16x32_bf16(afs, bfragb, acc, 0, 0, 0);
#pragma unroll
            for (int c = 0; c < 8; ++c) {
                bf16x8 af = *(const bf16x8*)(arow + c * 64 + q * 16);
                acc = __builtin_amdgcn_mfma_f32_16x16x32_bf16(af, bfrag[c], acc, 0, 0, 0);
            }
#pragma unroll
            for (int reg = 0; reg < 4; ++reg) {
                int vr = tile * 16 + q * 4 + reg;
                if (vr < p.N) {
                    float cdeg = (float)p.deg[vr]; cdeg = cdeg > 1.f ? cdeg : 1.f;
                    float h = acc[reg] / cdeg + p.r2[(size_t)vr * 16 + m];
                    h = h > 0.f ? h : 0.f;
                    p.out_h[(size_t)vr * 16 + m] = h;
                }
            }
        }
    }
    grid.sync();

    // ---- P8: global mean pool (first Bg blocks) ----
    if ((int)blockIdx.x < p.Bg) {
        const int b = blockIdx.x;
        int lo = 0, hi = p.N;
        while (lo < hi) { int mid = (lo + hi) >> 1; if (p.batch[mid] < b) lo = mid + 1; else hi = mid; }
        const int start = lo;
        hi = p.N;
        while (lo < hi) { int mid = (lo + hi) >> 1; if (p.batch[mid] < b + 1) lo = mid + 1; else hi = mid; }
        const int end = lo;

        const int ch = threadIdx.x & 15, grp = threadIdx.x >> 4;
        float acc = 0.f;
        for (int v = start + grp; v < end; v += 16)
            acc += p.out_h[(size_t)v * 16 + ch];

        float* red = (float*)smem;
        red[threadIdx.x] = acc;
        __syncthreads();
#pragma unroll
        for (int sh = 128; sh >= 16; sh >>= 1) {
            if (threadIdx.x < sh) red[threadIdx.x] += red[threadIdx.x + sh];
            __syncthreads();
        }
        if (threadIdx.x < 16) {
            float cdeg = (float)(end - start); cdeg = cdeg > 1.f ? cdeg : 1.f;
            p.out_g[b * 16 + threadIdx.x] = red[threadIdx.x] / cdeg;
        }
    }
}

extern "C" void kernel_launch(void* const* d_in, const int* in_sizes, int n_in,
                              void* d_out, int out_size, void* d_ws, size_t ws_size,
                              hipStream_t stream)
{
    const int E = in_sizes[1];        // 800000
    const int N = in_sizes[15];       // 50000
    const int Bg = (out_size - N * 16 - N) / 16;   // 64
    const int ntiles = (N + 15) / 16;
    const int npad = ntiles * 16;

    auto align16 = [](size_t v) { return (v + 15) & ~(size_t)15; };

    char* ws = (char*)d_ws;
    size_t off = 0;
    int*   deg    = (int*)(ws + off);  off = align16(off + (size_t)N * 4);
    int*   rowptr = (int*)(ws + off);  off = align16(off + (size_t)(N + 1) * 4);
    int*   cursor = (int*)(ws + off);  off = align16(off + (size_t)N * 4);
    int*   bsum   = (int*)(ws + off);  off = align16(off + 256 * 4);
    int*   boff   = (int*)(ws + off);  off = align16(off + 256 * 4);
    long long* edat = (long long*)(ws + off); off = align16(off + (size_t)E * 8);
    char*  U1     = ws + off;          off = align16(off + (size_t)npad * 256);
    char*  S1     = ws + off;          off = align16(off + (size_t)npad * 16);
    char*  U2     = ws + off;          off = align16(off + (size_t)npad * 512);
    char*  S2     = ws + off;          off = align16(off + (size_t)npad * 32);
    float* r1     = (float*)(ws + off); off = align16(off + (size_t)N * 16 * 4);
    float* h1     = (float*)(ws + off); off = align16(off + (size_t)N * 16 * 4);
    float* r2     = (float*)(ws + off); off = align16(off + (size_t)N * 16 * 4);

    MegaParams p;
    p.x     = (const float*)d_in[0];
    p.ea    = (const float*)d_in[1];
    p.W_e1a = (const float*)d_in[2];
    p.b_e1a = (const float*)d_in[3];
    p.W_e1b = (const float*)d_in[4];
    p.b_e1b = (const float*)d_in[5];
    p.root1 = (const float*)d_in[6];
    p.bias1 = (const float*)d_in[7];
    p.W_e2a = (const float*)d_in[8];
    p.b_e2a = (const float*)d_in[9];
    p.W_e2b = (const float*)d_in[10];
    p.b_e2b = (const float*)d_in[11];
    p.root2 = (const float*)d_in[12];
    p.bias2 = (const float*)d_in[13];
    p.eidx  = (const int*)d_in[14];
    p.batch = (const int*)d_in[15];
    p.deg = deg; p.rowptr = rowptr; p.cursor = cursor; p.bsum = bsum; p.boff = boff;
    p.edat = edat; p.U1 = U1; p.S1 = S1; p.U2 = U2; p.S2 = S2;
    p.r1 = r1; p.h1 = h1; p.r2 = r2;
    p.out_h = (float*)d_out;
    p.out_g = p.out_h + (size_t)N * 16;
    p.out_b = p.out_g + (size_t)Bg * 16;
    p.N = N; p.E = E; p.Bg = Bg; p.ntiles = ntiles;
    p.scanBlocks = (N + 255) / 256;

    // grid sized to guaranteed co-residency (cooperative launch validates)
    static int gridBlocks = 0;
    if (gridBlocks == 0) {
        int perCU = 0;
        hipOccupancyMaxActiveBlocksPerMultiprocessor(&perCU,
            reinterpret_cast<const void*>(mega), 256, 0);
        if (perCU < 1) perCU = 1;
        if (perCU > 4) perCU = 4;
        hipDeviceProp_t prop{};
        int dev = 0;
        hipGetDevice(&dev);
        hipGetDeviceProperties(&prop, dev);
        int ncu = prop.multiProcessorCount > 0 ? prop.multiProcessorCount : 256;
        gridBlocks = ncu * perCU;
        if (gridBlocks > 2048) gridBlocks = 2048;
        if (gridBlocks < 256)  gridBlocks = 256;
    }

    void* args[] = { &p };
    hipLaunchCooperativeKernel(reinterpret_cast<const void*>(mega),
                               dim3(gridBlocks), dim3(256), args, 0, stream);
}

// Round 7
// 349.223 us; speedup vs baseline: 2.9590x; 2.9590x over previous
//
#include <hip/hip_runtime.h>
#include <hip/hip_bf16.h>

typedef __bf16 bf16;
typedef __bf16 bf16x8 __attribute__((ext_vector_type(8)));
typedef float  f32x4  __attribute__((ext_vector_type(4)));

// ---------------------------------------------------------------------------
// NNConv, round 7: revert to the r1 skeleton (best measured, 282-286us) and
// attack the MEASURED residual: ~12us x 8 inter-dispatch gaps (~90us).
// Pipeline shrunk 8 -> 5 graph nodes:
//   memset -> edge_l1 -> node_fin1 -> edge_l2 -> node_fin2_pool
//  * node_pre1 deleted: bias term folded into edge MFMA as extra K-slice
//    (r3-verified numerics); x@root1 recomputed in node_fin1.
//  * pool_seg deleted: pooling fused into node_fin2 via wave pre-combine +
//    workspace atomics + last-block-ticket finalize (no cooperative launch).
// Edge kernels: r1-verified structure (atomics, edat prefetch, 2048 blocks),
// minus the d1/d2 scalar gathers.
// ---------------------------------------------------------------------------

// Edge kernel layer 1: 16 edges/wave-tile, K=128 via 4x mfma + bias slice.
__global__ void edge_l1(const float* __restrict__ x,
                        const float* __restrict__ ea,
                        const int*   __restrict__ eidx,
                        const float* __restrict__ W_e1a, const float* __restrict__ b_e1a,
                        const float* __restrict__ W_e1b, const float* __restrict__ b_e1b,
                        float* __restrict__ agg, int* __restrict__ cnt,
                        int E, int ntiles)
{
    const int lane = threadIdx.x & 63;
    const int m = lane & 15;          // A row (edge in tile) / C col (out chan)
    const int q = lane >> 4;          // quad
    const int wave   = blockIdx.x * (blockDim.x >> 6) + (threadIdx.x >> 6);
    const int nwaves = gridDim.x * (blockDim.x >> 6);

    // B fragments: B[k][n] = W_e1b[(t*16+n)*16 + j], j=c*4+q, k=q*8+t (r1-verified)
    bf16x8 bfrag[4];
#pragma unroll
    for (int c = 0; c < 4; ++c)
#pragma unroll
        for (int t = 0; t < 8; ++t)
            bfrag[c][t] = (bf16)W_e1b[(t * 16 + m) * 16 + (c * 4 + q)];

    // bias slice (r3-verified): active only on q==0 k-slots; A = x fragment
    bf16x8 bfragb;
#pragma unroll
    for (int t = 0; t < 8; ++t)
        bfragb[t] = (q == 0) ? (bf16)b_e1b[t * 16 + m] : (bf16)0.f;

    float wa[4], bb[4];
#pragma unroll
    for (int c = 0; c < 4; ++c) { wa[c] = W_e1a[c * 4 + q]; bb[c] = b_e1a[c * 4 + q]; }

    int tile = wave;
    if (tile >= ntiles) return;

    int e = tile * 16 + m;
    int s = __builtin_nontemporal_load(eidx + e);
    int d = __builtin_nontemporal_load(eidx + E + e);
    float t_ea = __builtin_nontemporal_load(ea + e);

    while (tile < ntiles) {
        const int ntile = tile + nwaves;
        int s_nx = s, d_nx = d; float ea_nx = t_ea;
        if (ntile < ntiles) {                       // prefetch next tile
            int en = ntile * 16 + m;
            s_nx  = __builtin_nontemporal_load(eidx + en);
            d_nx  = __builtin_nontemporal_load(eidx + E + en);
            ea_nx = __builtin_nontemporal_load(ea + en);
        }

        const float4* xp = (const float4*)(x + (size_t)s * 8);
        float4 x0 = xp[0], x1 = xp[1];
        float xv[8] = {x0.x, x0.y, x0.z, x0.w, x1.x, x1.y, x1.z, x1.w};

        int d_r[4];
#pragma unroll
        for (int reg = 0; reg < 4; ++reg)
            d_r[reg] = __shfl(d, q * 4 + reg, 64);

        float he[4];
#pragma unroll
        for (int c = 0; c < 4; ++c) {
            float h = wa[c] * t_ea + bb[c];
            he[c] = h > 0.f ? h : 0.f;
        }

        f32x4 acc = {0.f, 0.f, 0.f, 0.f};
        {   // bias K-slice
            bf16x8 afb;
#pragma unroll
            for (int t = 0; t < 8; ++t) afb[t] = (bf16)xv[t];
            acc = __builtin_amdgcn_mfma_f32_16x16x32_bf16(afb, bfragb, acc, 0, 0, 0);
        }
#pragma unroll
        for (int c = 0; c < 4; ++c) {
            bf16x8 afrag;
#pragma unroll
            for (int t = 0; t < 8; ++t) afrag[t] = (bf16)(he[c] * xv[t]);
            acc = __builtin_amdgcn_mfma_f32_16x16x32_bf16(afrag, bfrag[c], acc, 0, 0, 0);
        }

        if (q == 0) atomicAdd(&cnt[d], 1);   // count each edge once

#pragma unroll
        for (int reg = 0; reg < 4; ++reg)
            atomicAdd(&agg[d_r[reg] * 16 + m], acc[reg]);

        s = s_nx; d = d_nx; t_ea = ea_nx; tile = ntile;
    }
}

// Finalize layer 1 (recomputes x@root1+bias1 inline) + layer-2 r2 precompute.
__global__ void node_fin1(const float* __restrict__ agg, const int* __restrict__ cnt,
                          const float* __restrict__ x,
                          const float* __restrict__ root1, const float* __restrict__ bias1,
                          const float* __restrict__ root2, const float* __restrict__ bias2,
                          float* __restrict__ h1, float* __restrict__ r2, int N)
{
    int t = blockIdx.x * blockDim.x + threadIdx.x;
    int v = t >> 4, o = t & 15;
    if (v >= N) return;
    float r1v = bias1[o];
#pragma unroll
    for (int i = 0; i < 8; ++i)
        r1v += x[v * 8 + i] * root1[i * 16 + o];
    float c = (float)cnt[v]; c = c > 1.f ? c : 1.f;
    float h = agg[v * 16 + o] / c + r1v;
    h = h > 0.f ? h : 0.f;
    h1[v * 16 + o] = h;
    float racc = bias2[o];
#pragma unroll
    for (int i = 0; i < 16; ++i)
        racc += __shfl(h, i, 16) * root2[i * 16 + o];
    r2[v * 16 + o] = racc;
}

// Edge kernel layer 2: K=256 via 8x mfma + bias slice.
__global__ void edge_l2(const float* __restrict__ h1g,
                        const float* __restrict__ ea,
                        const int*   __restrict__ eidx,
                        const float* __restrict__ W_e2a, const float* __restrict__ b_e2a,
                        const float* __restrict__ W_e2b, const float* __restrict__ b_e2b,
                        float* __restrict__ agg, int E, int ntiles)
{
    const int lane = threadIdx.x & 63;
    const int m = lane & 15;
    const int q = lane >> 4;
    const int qh = q >> 1;            // j = 2c + qh
    const int ql = q & 1;             // i = ql*8 + t
    const int wave   = blockIdx.x * (blockDim.x >> 6) + (threadIdx.x >> 6);
    const int nwaves = gridDim.x * (blockDim.x >> 6);

    bf16x8 bfrag[8];
#pragma unroll
    for (int c = 0; c < 8; ++c) {
        int j = c * 2 + qh;
#pragma unroll
        for (int t = 0; t < 8; ++t) {
            int i = ql * 8 + t;
            bfrag[c][t] = (bf16)W_e2b[(i * 16 + m) * 16 + j];
        }
    }

    // bias slice (r3-verified): active only qh==0; A = h fragment
    bf16x8 bfragb;
#pragma unroll
    for (int t = 0; t < 8; ++t)
        bfragb[t] = (qh == 0) ? (bf16)b_e2b[(ql * 8 + t) * 16 + m] : (bf16)0.f;

    float wa[8], bb[8];
#pragma unroll
    for (int c = 0; c < 8; ++c) { wa[c] = W_e2a[c * 2 + qh]; bb[c] = b_e2a[c * 2 + qh]; }

    int tile = wave;
    if (tile >= ntiles) return;

    int e = tile * 16 + m;
    int s = __builtin_nontemporal_load(eidx + e);
    int d = __builtin_nontemporal_load(eidx + E + e);
    float t_ea = __builtin_nontemporal_load(ea + e);

    while (tile < ntiles) {
        const int ntile = tile + nwaves;
        int s_nx = s, d_nx = d; float ea_nx = t_ea;
        if (ntile < ntiles) {
            int en = ntile * 16 + m;
            s_nx  = __builtin_nontemporal_load(eidx + en);
            d_nx  = __builtin_nontemporal_load(eidx + E + en);
            ea_nx = __builtin_nontemporal_load(ea + en);
        }

        const float4* hp = (const float4*)(h1g + (size_t)s * 16 + ql * 8);
        float4 h0 = hp[0], h1v = hp[1];
        float hv[8] = {h0.x, h0.y, h0.z, h0.w, h1v.x, h1v.y, h1v.z, h1v.w};

        int d_r[4];
#pragma unroll
        for (int reg = 0; reg < 4; ++reg)
            d_r[reg] = __shfl(d, q * 4 + reg, 64);

        float he[8];
#pragma unroll
        for (int c = 0; c < 8; ++c) {
            float h = wa[c] * t_ea + bb[c];
            he[c] = h > 0.f ? h : 0.f;
        }

        f32x4 acc = {0.f, 0.f, 0.f, 0.f};
        {
            bf16x8 afb;
#pragma unroll
            for (int t = 0; t < 8; ++t) afb[t] = (bf16)hv[t];
            acc = __builtin_amdgcn_mfma_f32_16x16x32_bf16(afb, bfragb, acc, 0, 0, 0);
        }
#pragma unroll
        for (int c = 0; c < 8; ++c) {
            bf16x8 afrag;
#pragma unroll
            for (int t = 0; t < 8; ++t) afrag[t] = (bf16)(he[c] * hv[t]);
            acc = __builtin_amdgcn_mfma_f32_16x16x32_bf16(afrag, bfrag[c], acc, 0, 0, 0);
        }

#pragma unroll
        for (int reg = 0; reg < 4; ++reg)
            atomicAdd(&agg[d_r[reg] * 16 + m], acc[reg]);

        s = s_nx; d = d_nx; t_ea = ea_nx; tile = ntile;
    }
}

// Finalize layer 2 + fused global mean pool (wave pre-combine + ws atomics +
// last-block-ticket finalize). batch passthrough included.
__global__ void node_fin2_pool(const float* __restrict__ agg, const int* __restrict__ cnt,
                               const float* __restrict__ r2, const int* __restrict__ batch,
                               float* __restrict__ out_h, float* __restrict__ out_b,
                               float* __restrict__ poolsum, int* __restrict__ done,
                               float* __restrict__ out_g, int N, int Bg)
{
    const int t = blockIdx.x * blockDim.x + threadIdx.x;
    const int v = t >> 4, o = t & 15;
    const int lane = threadIdx.x & 63;
    const int q = lane >> 4;

    float h = 0.f; int b = 0;
    const bool valid = v < N;
    if (valid) {
        float c = (float)cnt[v]; c = c > 1.f ? c : 1.f;
        h = agg[v * 16 + o] / c + r2[v * 16 + o];
        h = h > 0.f ? h : 0.f;
        out_h[(size_t)v * 16 + o] = h;
        if (o == 0) out_b[v] = (float)batch[v];
        b = batch[v];
    }

    // pool: 4 nodes per wave; combine when same graph (common: ~780 nodes/graph)
    unsigned long long vb = __ballot(valid);
    int b0 = __shfl(b, 0, 64);
    if (vb == ~0ULL && __all(b == b0)) {
        h += __shfl_xor(h, 16, 64);
        h += __shfl_xor(h, 32, 64);
        if (q == 0) atomicAdd(&poolsum[b * 16 + o], h);
    } else if (valid) {
        atomicAdd(&poolsum[b * 16 + o], h);
    }

    // last-block finalize
    __shared__ int lastflag;
    __shared__ int gstart[257];
    __syncthreads();
    if (threadIdx.x == 0) {
        __threadfence();
        int tkt = atomicAdd(done, 1);
        lastflag = (tkt == (int)gridDim.x - 1) ? 1 : 0;
    }
    __syncthreads();
    if (!lastflag) return;

    for (int g = threadIdx.x; g <= Bg; g += blockDim.x) {
        int lo = 0, hi = N;
        while (lo < hi) { int mid = (lo + hi) >> 1; if (batch[mid] < g) lo = mid + 1; else hi = mid; }
        gstart[g] = lo;
    }
    __syncthreads();
    for (int idx = threadIdx.x; idx < Bg * 16; idx += blockDim.x) {
        int g = idx >> 4;
        float cg = (float)(gstart[g + 1] - gstart[g]); cg = cg > 1.f ? cg : 1.f;
        float sv = atomicAdd(&poolsum[idx], 0.f);   // coherent read
        out_g[idx] = sv / cg;
    }
}

extern "C" void kernel_launch(void* const* d_in, const int* in_sizes, int n_in,
                              void* d_out, int out_size, void* d_ws, size_t ws_size,
                              hipStream_t stream)
{
    const float* x     = (const float*)d_in[0];
    const float* ea    = (const float*)d_in[1];
    const float* W_e1a = (const float*)d_in[2];
    const float* b_e1a = (const float*)d_in[3];
    const float* W_e1b = (const float*)d_in[4];
    const float* b_e1b = (const float*)d_in[5];
    const float* root1 = (const float*)d_in[6];
    const float* bias1 = (const float*)d_in[7];
    const float* W_e2a = (const float*)d_in[8];
    const float* b_e2a = (const float*)d_in[9];
    const float* W_e2b = (const float*)d_in[10];
    const float* b_e2b = (const float*)d_in[11];
    const float* root2 = (const float*)d_in[12];
    const float* bias2 = (const float*)d_in[13];
    const int*   eidx  = (const int*)d_in[14];
    const int*   batch = (const int*)d_in[15];

    const int E  = in_sizes[1];       // 800000
    const int N  = in_sizes[15];      // 50000
    const int Bg = (out_size - N * 16 - N) / 16;   // 64

    auto align16 = [](size_t v) { return (v + 15) & ~(size_t)15; };

    char* ws = (char*)d_ws;
    size_t off = 0;
    int*   cnt     = (int*)(ws + off);   off = align16(off + (size_t)N * 4);
    float* agg1    = (float*)(ws + off); off = align16(off + (size_t)N * 16 * 4);
    float* agg2    = (float*)(ws + off); off = align16(off + (size_t)N * 16 * 4);
    float* poolsum = (float*)(ws + off); off = align16(off + (size_t)Bg * 16 * 4);
    int*   done    = (int*)(ws + off);   off = align16(off + 16);
    size_t zero_bytes = off;
    float* h1 = (float*)(ws + off); off = align16(off + (size_t)N * 16 * 4);
    float* r2 = (float*)(ws + off); off = align16(off + (size_t)N * 16 * 4);

    hipMemsetAsync(d_ws, 0, zero_bytes, stream);

    const int nodeBlocks = (N * 16 + 255) / 256;
    const int ntiles = E / 16;
    const int edgeBlocks = 2048;

    edge_l1<<<edgeBlocks, 256, 0, stream>>>(x, ea, eidx, W_e1a, b_e1a,
                                            W_e1b, b_e1b, agg1, cnt, E, ntiles);
    node_fin1<<<nodeBlocks, 256, 0, stream>>>(agg1, cnt, x, root1, bias1,
                                              root2, bias2, h1, r2, N);
    edge_l2<<<edgeBlocks, 256, 0, stream>>>(h1, ea, eidx, W_e2a, b_e2a,
                                            W_e2b, b_e2b, agg2, E, ntiles);

    float* out_h = (float*)d_out;
    float* out_g = out_h + (size_t)N * 16;
    float* out_b = out_g + (size_t)Bg * 16;
    node_fin2_pool<<<nodeBlocks, 256, 0, stream>>>(agg2, cnt, r2, batch,
                                                   out_h, out_b, poolsum, done,
                                                   out_g, N, Bg);
}